// Round 17
// baseline (97.751 us; speedup 1.0000x reference)
//
#include <hip/hip_runtime.h>
#include <hip/hip_bf16.h>

// Problem constants
#define B_    4
#define T_    4096
#define D_    1024
#define NH_   16
#define NS_   64
#define HD_   64
#define ALPHA_ 0.1f
#define M_    (B_*T_)        // 16384 rows
#define N_    (NH_*NS_)      // 1024 cols (head*slot)
#define NG_   256            // 16-t groups per (b,h)

typedef __attribute__((ext_vector_type(8))) short short8v;
typedef __attribute__((ext_vector_type(4))) float f32x4;
typedef _Float16 f16x8 __attribute__((ext_vector_type(8)));

__device__ inline unsigned short f2bf(float x) {
    unsigned u = __float_as_uint(x);
    unsigned r = u + 0x7FFF + ((u >> 16) & 1);   // RNE
    return (unsigned short)(r >> 16);
}

// ---------------------------------------------------------------------------
// Kernel 0: H fp32 -> bf16 (R14 version).
__global__ __launch_bounds__(256)
void k_h2bf(const float* __restrict__ H, unsigned short* __restrict__ Hb) {
    int idx = blockIdx.x * 256 + threadIdx.x;         // unit = 8 floats
    const int stride = 2048 * 256;
    #pragma unroll
    for (int it = 0; it < 4; ++it) {
        int e = (idx + it * stride) * 8;
        float4 f0 = *(const float4*)&H[e];
        float4 f1 = *(const float4*)&H[e + 4];
        __hip_bfloat162 q0 = __float22bfloat162_rn(make_float2(f0.x, f0.y));
        __hip_bfloat162 q1 = __float22bfloat162_rn(make_float2(f0.z, f0.w));
        __hip_bfloat162 q2 = __float22bfloat162_rn(make_float2(f1.x, f1.y));
        __hip_bfloat162 q3 = __float22bfloat162_rn(make_float2(f1.z, f1.w));
        uint4 u = {*(unsigned*)&q0, *(unsigned*)&q1, *(unsigned*)&q2, *(unsigned*)&q3};
        *(uint4*)&Hb[e] = u;
    }
}

// ---------------------------------------------------------------------------
// Kernel 1: fold W_tok into prototypes, emit bf16 (unchanged).
__global__ __launch_bounds__(256)
void k_protoproj(const float* __restrict__ proto,
                 const float* __restrict__ W,
                 unsigned short* __restrict__ Pb) {
    int bid = blockIdx.x;            // 256
    int h = bid >> 4, mr = bid & 15;
    int m0 = mr * 64;
    __shared__ float pl[64][68];
    __shared__ float Wl[64][68];
    int tid = threadIdx.x;
    int rr = tid >> 2, cg = (tid & 3) * 16;
    #pragma unroll
    for (int i = 0; i < 4; ++i)
        *(float4*)&pl[rr][cg + i * 4] =
            *(const float4*)&proto[rr * D_ + h * 64 + cg + i * 4];
    #pragma unroll
    for (int i = 0; i < 4; ++i)
        *(float4*)&Wl[rr][cg + i * 4] =
            *(const float4*)&W[(h * 64 + rr) * D_ + m0 + cg + i * 4];
    __syncthreads();
    int s = tid & 63, mg = (tid >> 6) * 16;
    float acc[16] = {};
    for (int k = 0; k < 64; ++k) {
        float pv = pl[s][k];
        #pragma unroll
        for (int i = 0; i < 16; ++i) acc[i] += pv * Wl[k][mg + i];
    }
    unsigned short ob[16];
    #pragma unroll
    for (int i = 0; i < 16; ++i) ob[i] = f2bf(0.125f * acc[i]);
    unsigned short* dst = &Pb[(size_t)(h * 64 + s) * D_ + m0 + mg];
    *(uint4*)dst       = *(uint4*)&ob[0];
    *(uint4*)(dst + 8) = *(uint4*)&ob[8];
}

// ---------------------------------------------------------------------------
// Kernel 2 (v9): bf16 MFMA GEMM, 256x256 tile, counted-vmcnt pipeline
// + fused epilogue emitting PER-16-ROW g-products cp16 (R16's epilogue at
// m-frag granularity; enables ppl-free k_out).
#define GFENCE  __builtin_amdgcn_sched_barrier(0)

__global__ __launch_bounds__(512, 2)
void k_gemm(const unsigned short* __restrict__ Ab,   // Hb [M_, D_] bf16
            const unsigned short* __restrict__ Bp,   // Pb [N_, D_] bf16
            _Float16* __restrict__ C,                // scores [M_, N_] f16
            float* __restrict__ cp16) {              // [B*NH, NG_, 64]
    extern __shared__ unsigned short lds[];
    unsigned short* AsB[2] = {lds,         lds + 16384};   // 2 x 32 KB
    unsigned short* BsB[2] = {lds + 32768, lds + 49152};   // 2 x 32 KB
    int tid = threadIdx.x;                // 0..511
    int bid = blockIdx.x;                 // 0..255
    int wgid = (bid & 7) * 32 + (bid >> 3);
    int bm = wgid >> 2, bn = wgid & 3;    // 64 m-blocks, 4 n-blocks
    int m0 = bm * 256, n0 = bn * 256;
    int l = tid & 63, wv = tid >> 6;      // 8 waves
    int wr = wv >> 2, wc = wv & 3;        // 2M x 4N
    int lr = l & 15, lk = l >> 4;

    int srow = tid >> 3;
    int skgs = (tid & 7) ^ (srow & 7);    // pre-swizzled global 16B group
    const unsigned short* Ap = Ab + (size_t)(m0 + srow) * D_ + skgs * 8;
    const unsigned short* Bq = Bp + (size_t)(n0 + srow) * D_ + skgs * 8;

    f32x4 acc[8][4];
    #pragma unroll
    for (int i = 0; i < 8; ++i)
        #pragma unroll
        for (int j = 0; j < 4; ++j) acc[i][j] = (f32x4){0.f, 0.f, 0.f, 0.f};

#define GSTAGE(BUF, K0)                                                         \
    _Pragma("unroll")                                                           \
    for (int i = 0; i < 4; ++i) {                                               \
        __builtin_amdgcn_global_load_lds(                                       \
            (const __attribute__((address_space(1))) void*)(Ap + (size_t)(i * 64) * D_ + (K0)), \
            (__attribute__((address_space(3))) void*)(&AsB[BUF][tid * 8 + i * 4096]), 16, 0, 0); \
        __builtin_amdgcn_global_load_lds(                                       \
            (const __attribute__((address_space(1))) void*)(Bq + (size_t)(i * 64) * D_ + (K0)), \
            (__attribute__((address_space(3))) void*)(&BsB[BUF][tid * 8 + i * 4096]), 16, 0, 0); \
    }

#define KSTEP(BUF)                                                              \
    {                                                                           \
        short8v bfr[4][2];                                                      \
        _Pragma("unroll")                                                       \
        for (int n = 0; n < 4; ++n)                                             \
            _Pragma("unroll")                                                   \
            for (int kk = 0; kk < 2; ++kk)                                      \
                bfr[n][kk] = *(const short8v*)&BsB[BUF][                        \
                    (wc * 64 + n * 16 + lr) * 64 + ((kk * 4 + lk) ^ (lr & 7)) * 8]; \
        _Pragma("unroll")                                                       \
        for (int m = 0; m < 8; ++m) {                                           \
            short8v af0 = *(const short8v*)&AsB[BUF][                           \
                (wr * 128 + m * 16 + lr) * 64 + ((lk) ^ (lr & 7)) * 8];         \
            short8v af1 = *(const short8v*)&AsB[BUF][                           \
                (wr * 128 + m * 16 + lr) * 64 + ((4 + lk) ^ (lr & 7)) * 8];     \
            _Pragma("unroll")                                                   \
            for (int n = 0; n < 4; ++n) {                                       \
                acc[m][n] = __builtin_amdgcn_mfma_f32_16x16x32_bf16(            \
                    af0, bfr[n][0], acc[m][n], 0, 0, 0);                        \
                acc[m][n] = __builtin_amdgcn_mfma_f32_16x16x32_bf16(            \
                    af1, bfr[n][1], acc[m][n], 0, 0, 0);                        \
            }                                                                   \
        }                                                                       \
    }

#define WAITC(N)  asm volatile("s_waitcnt vmcnt(" #N ")" ::: "memory")
#define BARRIER   GFENCE; __builtin_amdgcn_s_barrier(); GFENCE

    GSTAGE(0, 0)                          // prologue: tile 0 (8 loads)
    for (int t = 0; t < 14; t += 2) {
        GSTAGE(1, (t + 1) * 64)           // tile t+1 -> buf1 (8 in flight)
        WAITC(8);                         // tile t home; t+1 stays in flight
        BARRIER;
        KSTEP(0)
        BARRIER;
        GSTAGE(0, (t + 2) * 64)           // tile t+2 -> buf0
        WAITC(8);                         // tile t+1 home
        BARRIER;
        KSTEP(1)
        BARRIER;
    }
    GSTAGE(1, 15 * 64)
    WAITC(8);
    BARRIER;
    KSTEP(0)                              // tile 14
    BARRIER;
    WAITC(0);
    BARRIER;
    KSTEP(1)                              // tile 15
#undef GSTAGE
#undef KSTEP
#undef WAITC
#undef BARRIER

    // ---- epilogue: store raw f16 scores + per-16-row g-products ----
    // acc[m][n][j]: row = m0 + wr*128 + m*16 + lk*4 + j
    //               col = n0 + wc*64  + n*16 + lr   (wave's 64 cols = 1 head)
    int crow = m0 + wr * 128 + lk * 4;
    int ccol = n0 + wc * 64 + lr;
    float pch[8][4];                      // [m-frag = 16-row group][n]
    #pragma unroll
    for (int m = 0; m < 8; ++m)
        #pragma unroll
        for (int n = 0; n < 4; ++n) pch[m][n] = 1.f;

    #pragma unroll
    for (int m = 0; m < 8; ++m) {
        #pragma unroll
        for (int j = 0; j < 4; ++j) {
            _Float16 s4[4]; float e[4]; float ps = 0.f;
            #pragma unroll
            for (int n = 0; n < 4; ++n) {
                s4[n] = (_Float16)acc[m][n][j];     // f16 rounding = S numerics
                C[(size_t)(crow + m * 16 + j) * N_ + ccol + n * 16] = s4[n];
                e[n] = __expf((float)s4[n]);
                ps += e[n];
            }
            ps += __shfl_xor(ps, 1); ps += __shfl_xor(ps, 2);
            ps += __shfl_xor(ps, 4); ps += __shfl_xor(ps, 8);
            float inv = 1.f / ps;
            #pragma unroll
            for (int n = 0; n < 4; ++n)
                pch[m][n] *= 1.f - ALPHA_ * (e[n] * inv);
        }
    }
    // combine the 4 lk row-groups (rows interleave across lanes 16 apart)
    #pragma unroll
    for (int m = 0; m < 8; ++m)
        #pragma unroll
        for (int n = 0; n < 4; ++n) {
            pch[m][n] *= __shfl_xor(pch[m][n], 16);
            pch[m][n] *= __shfl_xor(pch[m][n], 32);
        }
    if (lk == 0) {
        int b  = bm >> 4;
        int h  = bn * 4 + wc;
        int bh = b * NH_ + h;
        int gbase = (bm & 15) * 16 + wr * 8;    // 16-row group base in batch
        #pragma unroll
        for (int m = 0; m < 8; ++m)
            #pragma unroll
            for (int n = 0; n < 4; ++n)
                cp16[(size_t)(bh * NG_ + gbase + m) * 64 + n * 16 + lr] = pch[m][n];
    }
}

// ---------------------------------------------------------------------------
// Kernel 3 (v4): parallel EXCLUSIVE suffix scan over 256 16-row groups,
// LDS-staged (R14 style — R15's LDS-free variant was latency-bound).
__global__ __launch_bounds__(256)
void k_scan(const float* __restrict__ cp16, float* __restrict__ csuf16) {
    int bh = blockIdx.x;                  // 64
    __shared__ float buf[NG_][64];        // 64 KB
    __shared__ float segp[4][64];
    int tid = threadIdx.x;
    #pragma unroll
    for (int i = 0; i < 16; ++i) {
        int e = tid * 4 + i * 1024;
        int g = e >> 6, sc = e & 63;
        *(float4*)&buf[g][sc] = *(const float4*)&cp16[((size_t)bh * NG_ + g) * 64 + sc];
    }
    __syncthreads();
    int s = tid & 63, seg = tid >> 6;
    float pp = 1.f;
    #pragma unroll 8
    for (int g = 0; g < 64; ++g) pp *= buf[seg * 64 + g][s];
    segp[seg][s] = pp;
    __syncthreads();
    float suf = 1.f;
    if (seg <= 2) suf *= segp[3][s];
    if (seg <= 1) suf *= segp[2][s];
    if (seg == 0) suf *= segp[1][s];
    #pragma unroll 8
    for (int g = 63; g >= 0; --g) {
        int gg = seg * 64 + g;
        csuf16[((size_t)bh * NG_ + gg) * 64 + s] = suf;   // EXCLUSIVE suffix
        suf *= buf[gg][s];
    }
}

// ---------------------------------------------------------------------------
// Kernel 4 (v9): softmax + weff walk + MFMA output accumulation.
// ppl phase + barrier C eliminated (walk starts from csuf16 directly);
// 2 barriers/iter (8 total vs 12). Otherwise R16's k_out.
__global__ __launch_bounds__(256)
void k_out_mfma(const _Float16* __restrict__ S,       // raw scores
                const unsigned short* __restrict__ Hb,// bf16 H
                const float* __restrict__ csuf16,
                float* __restrict__ out) {
    int bx = blockIdx.x;                  // 1024
    int cf = bx & 15, h = (bx >> 4) & 15, b = bx >> 8;
    __shared__ _Float16 ws16[64][72];           // softmaxed w
    __shared__ unsigned short tmp[64][72];      // staged Hb rows
    __shared__ _Float16 wt[8 * 64 * 8];         // w_eff^T subtiled [tg][s][8]
    __shared__ _Float16 hd[8 * 64 * 8];         // H^T    subtiled [tg][d][8]
    int tid = threadIdx.x;
    int lr0 = tid >> 3, lc = (tid & 7) * 8;     // load role: rows lr0, lr0+32
    int s = tid & 63, q = tid >> 6;             // walk/transpose role
    int fr = s & 15, fk = s >> 4, wv = q;       // mfma role

    // T14: issue it=0 loads first so they overlap the csuf16 loads
    size_t rr0 = (size_t)(b * T_ + cf * 256 + lr0) * N_ + h * 64 + lc;
    f16x8  sv0 = *(const f16x8*)(S + rr0);
    f16x8  sv1 = *(const f16x8*)(S + rr0 + (size_t)32 * N_);
    short8v hv0 = *(const short8v*)(Hb + rr0);
    short8v hv1 = *(const short8v*)(Hb + rr0 + (size_t)32 * N_);

    // prologue: per-iter walk start — group (within bh) = cf*16 + it*4 + q
    size_t gb = ((size_t)(b * NH_ + h) * NG_ + cf * 16) * 64 + s;
    float su16[4];
    #pragma unroll
    for (int it = 0; it < 4; ++it)
        su16[it] = csuf16[gb + (size_t)(it * 4 + q) * 64];

    f32x4 acc[4];
    #pragma unroll
    for (int n = 0; n < 4; ++n) acc[n] = (f32x4){0.f, 0.f, 0.f, 0.f};

    for (int it = 0; it < 4; ++it) {
        // softmax per row (8-lane group, no max-sub; |score| small)
        _Float16 w0[8], w1[8];
        {
            float e[8]; float ps = 0.f;
            #pragma unroll
            for (int j = 0; j < 8; ++j) { e[j] = __expf((float)sv0[j]); ps += e[j]; }
            ps += __shfl_xor(ps, 1); ps += __shfl_xor(ps, 2); ps += __shfl_xor(ps, 4);
            float inv = 1.f / ps;
            #pragma unroll
            for (int j = 0; j < 8; ++j) w0[j] = (_Float16)(e[j] * inv);
        }
        {
            float e[8]; float ps = 0.f;
            #pragma unroll
            for (int j = 0; j < 8; ++j) { e[j] = __expf((float)sv1[j]); ps += e[j]; }
            ps += __shfl_xor(ps, 1); ps += __shfl_xor(ps, 2); ps += __shfl_xor(ps, 4);
            float inv = 1.f / ps;
            #pragma unroll
            for (int j = 0; j < 8; ++j) w1[j] = (_Float16)(e[j] * inv);
        }
        // (no barrier: prior iter's barrier D ordered all ws16/tmp readers;
        //  MFMA between D and here reads only wt/hd)
        *(f16x8*)&ws16[lr0][lc]      = *(f16x8*)w0;
        *(f16x8*)&ws16[lr0 + 32][lc] = *(f16x8*)w1;
        *(short8v*)&tmp[lr0][lc]      = hv0;
        *(short8v*)&tmp[lr0 + 32][lc] = hv1;
        __syncthreads();                  // B: ws16 + tmp visible
        // T14: issue next iteration's loads now (regs free, latency hidden)
        if (it < 3) {
            size_t rn = rr0 + (size_t)((it + 1) * 64) * N_;
            sv0 = *(const f16x8*)(S + rn);
            sv1 = *(const f16x8*)(S + rn + (size_t)32 * N_);
            hv0 = *(const short8v*)(Hb + rn);
            hv1 = *(const short8v*)(Hb + rn + (size_t)32 * N_);
        }
        // transpose Hb: thread (q,s): tg = q and q+4, cvt bf16 -> f16
        #pragma unroll
        for (int x = 0; x < 2; ++x) {
            int tg = q + x * 4;
            _Float16 hreg[8];
            #pragma unroll
            for (int r = 0; r < 8; ++r) {
                unsigned short ub = tmp[tg * 8 + r][s];
                hreg[r] = (_Float16)__uint_as_float((unsigned)ub << 16);
            }
            *(f16x8*)&hd[(tg * 64 + s) * 8] = *(f16x8*)hreg;
        }
        // walk: rows q*16..q*16+15 backward, starting from csuf16 (no ppl)
        {
            float suf = su16[it];
            _Float16 wr16[16];
            #pragma unroll
            for (int r = 15; r >= 0; --r) {
                float wv_ = (float)ws16[q * 16 + r][s];
                wr16[r] = (_Float16)(ALPHA_ * wv_ * suf);
                suf *= 1.f - ALPHA_ * wv_;
            }
            *(f16x8*)&wt[((2 * q)     * 64 + s) * 8] = *(f16x8*)&wr16[0];
            *(f16x8*)&wt[((2 * q + 1) * 64 + s) * 8] = *(f16x8*)&wr16[8];
        }
        __syncthreads();                  // D: wt + hd visible
        // MFMA: wave wv -> s-block wv*16, all 64 d; K=64 = 2 k-steps
        #pragma unroll
        for (int kk = 0; kk < 2; ++kk) {
            int tg = kk * 4 + fk;
            f16x8 af = *(const f16x8*)&wt[(tg * 64 + wv * 16 + fr) * 8];
            #pragma unroll
            for (int n = 0; n < 4; ++n) {
                f16x8 bf = *(const f16x8*)&hd[(tg * 64 + n * 16 + fr) * 8];
                acc[n] = __builtin_amdgcn_mfma_f32_16x16x32_f16(
                    af, bf, acc[n], 0, 0, 0);
            }
        }
    }
    // D layout: row (s-dim) = fk*4 + j, col (d-dim) = fr
    #pragma unroll
    for (int n = 0; n < 4; ++n)
        #pragma unroll
        for (int j = 0; j < 4; ++j)
            atomicAdd(&out[((b * NS_ + wv * 16 + fk * 4 + j) * NH_ + h) * HD_
                           + n * 16 + fr],
                      acc[n][j]);
}

// ---------------------------------------------------------------------------
extern "C" void kernel_launch(void* const* d_in, const int* in_sizes, int n_in,
                              void* d_out, int out_size, void* d_ws, size_t ws_size,
                              hipStream_t stream) {
    const float* H     = (const float*)d_in[0];
    const float* proto = (const float*)d_in[1];
    const float* W     = (const float*)d_in[2];
    float* out = (float*)d_out;
    char*  ws  = (char*)d_ws;

    _Float16*       S  = (_Float16*)ws;                                  // 32 MB
    unsigned short* Hb = (unsigned short*)(ws + (size_t)M_ * N_ * 2);    // 32 MB
    unsigned short* Pb = (unsigned short*)(ws + (size_t)M_ * N_ * 2
                                              + (size_t)M_ * D_ * 2);    // 2 MB
    float* cp16   = (float*)((char*)Pb + (size_t)N_ * D_ * 2);           // 4 MB
    float* csuf16 = cp16 + (size_t)B_ * NH_ * NG_ * 64;                  // 4 MB

    // allow 128 KB dynamic LDS for the 256^2 GEMM (host-side, capture-safe)
    hipFuncSetAttribute((const void*)k_gemm,
                        hipFuncAttributeMaxDynamicSharedMemorySize, 131072);

    hipMemsetAsync(d_out, 0, (size_t)out_size * sizeof(float), stream);

    k_h2bf      <<<2048,      256, 0,      stream>>>(H, Hb);
    k_protoproj <<<256,       256, 0,      stream>>>(proto, W, Pb);
    k_gemm      <<<256,       512, 131072, stream>>>(Hb, Pb, S, cp16);
    k_scan      <<<B_*NH_,    256, 0,      stream>>>(cp16, csuf16);
    k_out_mfma  <<<B_*NH_*16, 256, 0,      stream>>>(S, Hb, csuf16, out);
}

// Round 18
// 91.552 us; speedup vs baseline: 1.0677x; 1.0677x over previous
//
#include <hip/hip_runtime.h>
#include <hip/hip_bf16.h>

// Problem constants
#define B_    4
#define T_    4096
#define D_    1024
#define NH_   16
#define NS_   64
#define HD_   64
#define ALPHA_ 0.1f
#define M_    (B_*T_)        // 16384 rows
#define N_    (NH_*NS_)      // 1024 cols (head*slot)
#define NCH_  128            // 32-t chunks
#define CHUNK_ 32

typedef __attribute__((ext_vector_type(8))) short short8v;
typedef __attribute__((ext_vector_type(4))) float f32x4;
typedef _Float16 f16x8 __attribute__((ext_vector_type(8)));

__device__ inline unsigned short f2bf(float x) {
    unsigned u = __float_as_uint(x);
    unsigned r = u + 0x7FFF + ((u >> 16) & 1);   // RNE
    return (unsigned short)(r >> 16);
}

// ---------------------------------------------------------------------------
// Kernel 0: H fp32 -> bf16.
__global__ __launch_bounds__(256)
void k_h2bf(const float* __restrict__ H, unsigned short* __restrict__ Hb) {
    int idx = blockIdx.x * 256 + threadIdx.x;         // unit = 8 floats
    const int stride = 2048 * 256;
    #pragma unroll
    for (int it = 0; it < 4; ++it) {
        int e = (idx + it * stride) * 8;
        float4 f0 = *(const float4*)&H[e];
        float4 f1 = *(const float4*)&H[e + 4];
        __hip_bfloat162 q0 = __float22bfloat162_rn(make_float2(f0.x, f0.y));
        __hip_bfloat162 q1 = __float22bfloat162_rn(make_float2(f0.z, f0.w));
        __hip_bfloat162 q2 = __float22bfloat162_rn(make_float2(f1.x, f1.y));
        __hip_bfloat162 q3 = __float22bfloat162_rn(make_float2(f1.z, f1.w));
        uint4 u = {*(unsigned*)&q0, *(unsigned*)&q1, *(unsigned*)&q2, *(unsigned*)&q3};
        *(uint4*)&Hb[e] = u;
    }
}

// ---------------------------------------------------------------------------
// Kernel 1: fold W_tok into prototypes, emit bf16 + zero d_out (folded
// memset: 256 blocks x 256 threads x float4 = exactly the 1 MB output;
// stream-ordered ahead of k_out's atomics, zero LDS/occupancy impact).
__global__ __launch_bounds__(256)
void k_protoproj(const float* __restrict__ proto,
                 const float* __restrict__ W,
                 unsigned short* __restrict__ Pb,
                 float* __restrict__ outp) {
    int bid = blockIdx.x;            // 256
    int tid = threadIdx.x;
    *(float4*)&outp[bid * 1024 + tid * 4] = (float4){0.f, 0.f, 0.f, 0.f};
    int h = bid >> 4, mr = bid & 15;
    int m0 = mr * 64;
    __shared__ float pl[64][68];
    __shared__ float Wl[64][68];
    int rr = tid >> 2, cg = (tid & 3) * 16;
    #pragma unroll
    for (int i = 0; i < 4; ++i)
        *(float4*)&pl[rr][cg + i * 4] =
            *(const float4*)&proto[rr * D_ + h * 64 + cg + i * 4];
    #pragma unroll
    for (int i = 0; i < 4; ++i)
        *(float4*)&Wl[rr][cg + i * 4] =
            *(const float4*)&W[(h * 64 + rr) * D_ + m0 + cg + i * 4];
    __syncthreads();
    int s = tid & 63, mg = (tid >> 6) * 16;
    float acc[16] = {};
    for (int k = 0; k < 64; ++k) {
        float pv = pl[s][k];
        #pragma unroll
        for (int i = 0; i < 16; ++i) acc[i] += pv * Wl[k][mg + i];
    }
    unsigned short ob[16];
    #pragma unroll
    for (int i = 0; i < 16; ++i) ob[i] = f2bf(0.125f * acc[i]);
    unsigned short* dst = &Pb[(size_t)(h * 64 + s) * D_ + m0 + mg];
    *(uint4*)dst       = *(uint4*)&ob[0];
    *(uint4*)(dst + 8) = *(uint4*)&ob[8];
}

// ---------------------------------------------------------------------------
// Kernel 2 (v8 = R16): bf16 MFMA GEMM, 256x256 tile, counted-vmcnt pipeline
// + fused k_cp epilogue (per-32-row chunk g-products). Measured best: 44.2 us.
#define GFENCE  __builtin_amdgcn_sched_barrier(0)

__global__ __launch_bounds__(512, 2)
void k_gemm(const unsigned short* __restrict__ Ab,   // Hb [M_, D_] bf16
            const unsigned short* __restrict__ Bp,   // Pb [N_, D_] bf16
            _Float16* __restrict__ C,                // scores [M_, N_] f16
            float* __restrict__ cp) {                // [B*NH, NCH, 64]
    extern __shared__ unsigned short lds[];
    unsigned short* AsB[2] = {lds,         lds + 16384};   // 2 x 32 KB
    unsigned short* BsB[2] = {lds + 32768, lds + 49152};   // 2 x 32 KB
    int tid = threadIdx.x;                // 0..511
    int bid = blockIdx.x;                 // 0..255
    int wgid = (bid & 7) * 32 + (bid >> 3);
    int bm = wgid >> 2, bn = wgid & 3;    // 64 m-blocks, 4 n-blocks
    int m0 = bm * 256, n0 = bn * 256;
    int l = tid & 63, wv = tid >> 6;      // 8 waves
    int wr = wv >> 2, wc = wv & 3;        // 2M x 4N
    int lr = l & 15, lk = l >> 4;

    int srow = tid >> 3;
    int skgs = (tid & 7) ^ (srow & 7);    // pre-swizzled global 16B group
    const unsigned short* Ap = Ab + (size_t)(m0 + srow) * D_ + skgs * 8;
    const unsigned short* Bq = Bp + (size_t)(n0 + srow) * D_ + skgs * 8;

    f32x4 acc[8][4];
    #pragma unroll
    for (int i = 0; i < 8; ++i)
        #pragma unroll
        for (int j = 0; j < 4; ++j) acc[i][j] = (f32x4){0.f, 0.f, 0.f, 0.f};

#define GSTAGE(BUF, K0)                                                         \
    _Pragma("unroll")                                                           \
    for (int i = 0; i < 4; ++i) {                                               \
        __builtin_amdgcn_global_load_lds(                                       \
            (const __attribute__((address_space(1))) void*)(Ap + (size_t)(i * 64) * D_ + (K0)), \
            (__attribute__((address_space(3))) void*)(&AsB[BUF][tid * 8 + i * 4096]), 16, 0, 0); \
        __builtin_amdgcn_global_load_lds(                                       \
            (const __attribute__((address_space(1))) void*)(Bq + (size_t)(i * 64) * D_ + (K0)), \
            (__attribute__((address_space(3))) void*)(&BsB[BUF][tid * 8 + i * 4096]), 16, 0, 0); \
    }

#define KSTEP(BUF)                                                              \
    {                                                                           \
        short8v bfr[4][2];                                                      \
        _Pragma("unroll")                                                       \
        for (int n = 0; n < 4; ++n)                                             \
            _Pragma("unroll")                                                   \
            for (int kk = 0; kk < 2; ++kk)                                      \
                bfr[n][kk] = *(const short8v*)&BsB[BUF][                        \
                    (wc * 64 + n * 16 + lr) * 64 + ((kk * 4 + lk) ^ (lr & 7)) * 8]; \
        _Pragma("unroll")                                                       \
        for (int m = 0; m < 8; ++m) {                                           \
            short8v af0 = *(const short8v*)&AsB[BUF][                           \
                (wr * 128 + m * 16 + lr) * 64 + ((lk) ^ (lr & 7)) * 8];         \
            short8v af1 = *(const short8v*)&AsB[BUF][                           \
                (wr * 128 + m * 16 + lr) * 64 + ((4 + lk) ^ (lr & 7)) * 8];     \
            _Pragma("unroll")                                                   \
            for (int n = 0; n < 4; ++n) {                                       \
                acc[m][n] = __builtin_amdgcn_mfma_f32_16x16x32_bf16(            \
                    af0, bfr[n][0], acc[m][n], 0, 0, 0);                        \
                acc[m][n] = __builtin_amdgcn_mfma_f32_16x16x32_bf16(            \
                    af1, bfr[n][1], acc[m][n], 0, 0, 0);                        \
            }                                                                   \
        }                                                                       \
    }

#define WAITC(N)  asm volatile("s_waitcnt vmcnt(" #N ")" ::: "memory")
#define BARRIER   GFENCE; __builtin_amdgcn_s_barrier(); GFENCE

    GSTAGE(0, 0)                          // prologue: tile 0 (8 loads)
    for (int t = 0; t < 14; t += 2) {
        GSTAGE(1, (t + 1) * 64)           // tile t+1 -> buf1 (8 in flight)
        WAITC(8);                         // tile t home; t+1 stays in flight
        BARRIER;
        KSTEP(0)
        BARRIER;
        GSTAGE(0, (t + 2) * 64)           // tile t+2 -> buf0
        WAITC(8);                         // tile t+1 home
        BARRIER;
        KSTEP(1)
        BARRIER;
    }
    GSTAGE(1, 15 * 64)
    WAITC(8);
    BARRIER;
    KSTEP(0)                              // tile 14
    BARRIER;
    WAITC(0);
    BARRIER;
    KSTEP(1)                              // tile 15
#undef GSTAGE
#undef KSTEP
#undef WAITC
#undef BARRIER

    // ---- epilogue: store raw f16 scores + fused per-chunk g-products ----
    // acc[m][n][j]: row = m0 + wr*128 + m*16 + lk*4 + j
    //               col = n0 + wc*64  + n*16 + lr   (wave's 64 cols = 1 head)
    int crow = m0 + wr * 128 + lk * 4;
    int ccol = n0 + wc * 64 + lr;
    float pch[4][4];                      // [chunk c2 = m>>1][n]
    #pragma unroll
    for (int c2 = 0; c2 < 4; ++c2)
        #pragma unroll
        for (int n = 0; n < 4; ++n) pch[c2][n] = 1.f;

    #pragma unroll
    for (int m = 0; m < 8; ++m) {
        #pragma unroll
        for (int j = 0; j < 4; ++j) {
            _Float16 s4[4]; float e[4]; float ps = 0.f;
            #pragma unroll
            for (int n = 0; n < 4; ++n) {
                s4[n] = (_Float16)acc[m][n][j];     // f16 rounding = S numerics
                C[(size_t)(crow + m * 16 + j) * N_ + ccol + n * 16] = s4[n];
                e[n] = __expf((float)s4[n]);
                ps += e[n];
            }
            ps += __shfl_xor(ps, 1); ps += __shfl_xor(ps, 2);
            ps += __shfl_xor(ps, 4); ps += __shfl_xor(ps, 8);
            float inv = 1.f / ps;
            int c2 = m >> 1;
            #pragma unroll
            for (int n = 0; n < 4; ++n)
                pch[c2][n] *= 1.f - ALPHA_ * (e[n] * inv);
        }
    }
    // combine the 4 lk row-groups (rows interleave across lanes 16 apart)
    #pragma unroll
    for (int c2 = 0; c2 < 4; ++c2)
        #pragma unroll
        for (int n = 0; n < 4; ++n) {
            pch[c2][n] *= __shfl_xor(pch[c2][n], 16);
            pch[c2][n] *= __shfl_xor(pch[c2][n], 32);
        }
    if (lk == 0) {
        int b  = bm >> 4;
        int h  = bn * 4 + wc;
        int bh = b * NH_ + h;
        int cb = (bm & 15) * 8 + wr * 4;  // chunk base within batch
        #pragma unroll
        for (int c2 = 0; c2 < 4; ++c2)
            #pragma unroll
            for (int n = 0; n < 4; ++n)
                cp[(size_t)(bh * NCH_ + cb + c2) * 64 + n * 16 + lr] = pch[c2][n];
    }
}

// ---------------------------------------------------------------------------
// Kernel 3b: PARALLEL cross-chunk exclusive suffix scan (R14/R16 LDS version).
__global__ __launch_bounds__(256)
void k_scan(const float* __restrict__ cp, float* __restrict__ csuf) {
    int bh = blockIdx.x;                  // 64
    __shared__ float buf[128][64];        // 32 KB
    __shared__ float segp[4][64];
    int tid = threadIdx.x;
    #pragma unroll
    for (int i = 0; i < 8; ++i) {
        int e = tid * 4 + i * 1024;
        int c = e >> 6, sc = e & 63;
        *(float4*)&buf[c][sc] = *(const float4*)&cp[(bh * NCH_ + c) * 64 + sc];
    }
    __syncthreads();
    int s = tid & 63, seg = tid >> 6;
    float pp = 1.f;
    #pragma unroll
    for (int r = 0; r < 32; ++r) pp *= buf[seg * 32 + r][s];
    segp[seg][s] = pp;
    __syncthreads();
    float suf = 1.f;
    if (seg <= 2) suf *= segp[3][s];
    if (seg <= 1) suf *= segp[2][s];
    if (seg == 0) suf *= segp[1][s];
    #pragma unroll
    for (int r = 31; r >= 0; --r) {
        int c = seg * 32 + r;
        csuf[(bh * NCH_ + c) * 64 + s] = suf;   // EXCLUSIVE suffix
        suf *= buf[c][s];
    }
}

// ---------------------------------------------------------------------------
// Kernel 4 (R16 version): softmax + weff walk + MFMA output accumulation.
__global__ __launch_bounds__(256)
void k_out_mfma(const _Float16* __restrict__ S,       // raw scores
                const unsigned short* __restrict__ Hb,// bf16 H
                const float* __restrict__ csuf,
                float* __restrict__ out) {
    int bx = blockIdx.x;                  // 1024
    int cf = bx & 15, h = (bx >> 4) & 15, b = bx >> 8;
    __shared__ _Float16 ws16[64][72];           // softmaxed w
    __shared__ unsigned short tmp[64][72];      // staged Hb rows
    __shared__ float ppl[4][64];                // per-16-row g partial products
    __shared__ _Float16 wt[8 * 64 * 8];         // w_eff^T subtiled [tg][s][8]
    __shared__ _Float16 hd[8 * 64 * 8];         // H^T    subtiled [tg][d][8]
    int tid = threadIdx.x;
    int lr0 = tid >> 3, lc = (tid & 7) * 8;     // load role: rows lr0, lr0+32
    int s = tid & 63, q = tid >> 6;             // walk/transpose role
    int fr = s & 15, fk = s >> 4, wv = q;       // mfma role

    // T14: issue it=0 loads first so they overlap the csuf loads
    size_t rr0 = (size_t)(b * T_ + cf * 256 + lr0) * N_ + h * 64 + lc;
    f16x8  sv0 = *(const f16x8*)(S + rr0);
    f16x8  sv1 = *(const f16x8*)(S + rr0 + (size_t)32 * N_);
    short8v hv0 = *(const short8v*)(Hb + rr0);
    short8v hv1 = *(const short8v*)(Hb + rr0 + (size_t)32 * N_);

    // prologue: su[k] = exclusive suffix of chunk (cf*8 + k)
    int cbase = (b * NH_ + h) * NCH_ + cf * 8;
    float su[8];
    #pragma unroll
    for (int k = 0; k < 8; ++k)
        su[k] = csuf[(cbase + k) * 64 + s];

    f32x4 acc[4];
    #pragma unroll
    for (int n = 0; n < 4; ++n) acc[n] = (f32x4){0.f, 0.f, 0.f, 0.f};

    for (int it = 0; it < 4; ++it) {
        // softmax per row (8-lane group, no max-sub; |score| small)
        _Float16 w0[8], w1[8];
        {
            float e[8]; float ps = 0.f;
            #pragma unroll
            for (int j = 0; j < 8; ++j) { e[j] = __expf((float)sv0[j]); ps += e[j]; }
            ps += __shfl_xor(ps, 1); ps += __shfl_xor(ps, 2); ps += __shfl_xor(ps, 4);
            float inv = 1.f / ps;
            #pragma unroll
            for (int j = 0; j < 8; ++j) w0[j] = (_Float16)(e[j] * inv);
        }
        {
            float e[8]; float ps = 0.f;
            #pragma unroll
            for (int j = 0; j < 8; ++j) { e[j] = __expf((float)sv1[j]); ps += e[j]; }
            ps += __shfl_xor(ps, 1); ps += __shfl_xor(ps, 2); ps += __shfl_xor(ps, 4);
            float inv = 1.f / ps;
            #pragma unroll
            for (int j = 0; j < 8; ++j) w1[j] = (_Float16)(e[j] * inv);
        }
        // (barrier A removed: prior iter's barrier D already ordered all
        //  ws16/tmp readers; MFMA between D and here reads only wt/hd)
        *(f16x8*)&ws16[lr0][lc]      = *(f16x8*)w0;
        *(f16x8*)&ws16[lr0 + 32][lc] = *(f16x8*)w1;
        *(short8v*)&tmp[lr0][lc]      = hv0;
        *(short8v*)&tmp[lr0 + 32][lc] = hv1;
        __syncthreads();                  // B: ws16 + tmp visible
        // T14: issue next iteration's loads now (regs free, latency hidden)
        if (it < 3) {
            size_t rn = rr0 + (size_t)((it + 1) * 64) * N_;
            sv0 = *(const f16x8*)(S + rn);
            sv1 = *(const f16x8*)(S + rn + (size_t)32 * N_);
            hv0 = *(const short8v*)(Hb + rn);
            hv1 = *(const short8v*)(Hb + rn + (size_t)32 * N_);
        }
        // ppl: partial product of g over this thread's 16 rows
        {
            float pp = 1.f;
            #pragma unroll
            for (int r = 0; r < 16; ++r)
                pp *= 1.f - ALPHA_ * (float)ws16[q * 16 + r][s];
            ppl[q][s] = pp;
        }
        // transpose Hb: thread (q,s): tg = q and q+4, cvt bf16 -> f16
        #pragma unroll
        for (int x = 0; x < 2; ++x) {
            int tg = q + x * 4;
            _Float16 hreg[8];
            #pragma unroll
            for (int r = 0; r < 8; ++r) {
                unsigned short ub = tmp[tg * 8 + r][s];
                hreg[r] = (_Float16)__uint_as_float((unsigned)ub << 16);
            }
            *(f16x8*)&hd[(tg * 64 + s) * 8] = *(f16x8*)hreg;
        }
        __syncthreads();                  // C: ppl + hd visible
        // walk: rows q*16..q*16+15 backward; chunk split at q<2 | q>=2
        {
            float suf = (q >= 2) ? su[it * 2 + 1] : su[it * 2];
            if (q == 2) suf *= ppl[3][s];
            if (q == 0) suf *= ppl[1][s];
            _Float16 wr16[16];
            #pragma unroll
            for (int r = 15; r >= 0; --r) {
                float wv_ = (float)ws16[q * 16 + r][s];
                wr16[r] = (_Float16)(ALPHA_ * wv_ * suf);
                suf *= 1.f - ALPHA_ * wv_;
            }
            *(f16x8*)&wt[((2 * q)     * 64 + s) * 8] = *(f16x8*)&wr16[0];
            *(f16x8*)&wt[((2 * q + 1) * 64 + s) * 8] = *(f16x8*)&wr16[8];
        }
        __syncthreads();                  // D: wt visible
        // MFMA: wave wv -> s-block wv*16, all 64 d; K=64 = 2 k-steps
        #pragma unroll
        for (int kk = 0; kk < 2; ++kk) {
            int tg = kk * 4 + fk;
            f16x8 af = *(const f16x8*)&wt[(tg * 64 + wv * 16 + fr) * 8];
            #pragma unroll
            for (int n = 0; n < 4; ++n) {
                f16x8 bf = *(const f16x8*)&hd[(tg * 64 + n * 16 + fr) * 8];
                acc[n] = __builtin_amdgcn_mfma_f32_16x16x32_f16(
                    af, bf, acc[n], 0, 0, 0);
            }
        }
    }
    // D layout: row (s-dim) = fk*4 + j, col (d-dim) = fr
    #pragma unroll
    for (int n = 0; n < 4; ++n)
        #pragma unroll
        for (int j = 0; j < 4; ++j)
            atomicAdd(&out[((b * NS_ + wv * 16 + fk * 4 + j) * NH_ + h) * HD_
                           + n * 16 + fr],
                      acc[n][j]);
}

// ---------------------------------------------------------------------------
extern "C" void kernel_launch(void* const* d_in, const int* in_sizes, int n_in,
                              void* d_out, int out_size, void* d_ws, size_t ws_size,
                              hipStream_t stream) {
    const float* H     = (const float*)d_in[0];
    const float* proto = (const float*)d_in[1];
    const float* W     = (const float*)d_in[2];
    float* out = (float*)d_out;
    char*  ws  = (char*)d_ws;

    _Float16*       S  = (_Float16*)ws;                                  // 32 MB
    unsigned short* Hb = (unsigned short*)(ws + (size_t)M_ * N_ * 2);    // 32 MB
    unsigned short* Pb = (unsigned short*)(ws + (size_t)M_ * N_ * 2
                                              + (size_t)M_ * D_ * 2);    // 2 MB
    float* cp   = (float*)((char*)Pb + (size_t)N_ * D_ * 2);             // 2 MB
    float* csuf = cp + (size_t)B_ * NH_ * NCH_ * 64;                     // 2 MB

    // allow 128 KB dynamic LDS for the 256^2 GEMM (host-side, capture-safe)
    hipFuncSetAttribute((const void*)k_gemm,
                        hipFuncAttributeMaxDynamicSharedMemorySize, 131072);

    k_h2bf      <<<2048,      256, 0,      stream>>>(H, Hb);
    k_protoproj <<<256,       256, 0,      stream>>>(proto, W, Pb, out);
    k_gemm      <<<256,       512, 131072, stream>>>(Hb, Pb, S, cp);
    k_scan      <<<B_*NH_,    256, 0,      stream>>>(cp, csuf);
    k_out_mfma  <<<B_*NH_*16, 256, 0,      stream>>>(S, Hb, csuf, out);
}

// Round 19
// 91.534 us; speedup vs baseline: 1.0679x; 1.0002x over previous
//
#include <hip/hip_runtime.h>
#include <hip/hip_bf16.h>

// Problem constants
#define B_    4
#define T_    4096
#define D_    1024
#define NH_   16
#define NS_   64
#define HD_   64
#define ALPHA_ 0.1f
#define M_    (B_*T_)        // 16384 rows
#define N_    (NH_*NS_)      // 1024 cols (head*slot)
#define NCH_  128            // 32-t chunks
#define CHUNK_ 32

typedef __attribute__((ext_vector_type(8))) short short8v;
typedef __attribute__((ext_vector_type(4))) float f32x4;
typedef _Float16 f16x8 __attribute__((ext_vector_type(8)));

__device__ inline unsigned short f2bf(float x) {
    unsigned u = __float_as_uint(x);
    unsigned r = u + 0x7FFF + ((u >> 16) & 1);   // RNE
    return (unsigned short)(r >> 16);
}

// ---------------------------------------------------------------------------
// Kernel 0: H fp32 -> bf16.
__global__ __launch_bounds__(256)
void k_h2bf(const float* __restrict__ H, unsigned short* __restrict__ Hb) {
    int idx = blockIdx.x * 256 + threadIdx.x;         // unit = 8 floats
    const int stride = 2048 * 256;
    #pragma unroll
    for (int it = 0; it < 4; ++it) {
        int e = (idx + it * stride) * 8;
        float4 f0 = *(const float4*)&H[e];
        float4 f1 = *(const float4*)&H[e + 4];
        __hip_bfloat162 q0 = __float22bfloat162_rn(make_float2(f0.x, f0.y));
        __hip_bfloat162 q1 = __float22bfloat162_rn(make_float2(f0.z, f0.w));
        __hip_bfloat162 q2 = __float22bfloat162_rn(make_float2(f1.x, f1.y));
        __hip_bfloat162 q3 = __float22bfloat162_rn(make_float2(f1.z, f1.w));
        uint4 u = {*(unsigned*)&q0, *(unsigned*)&q1, *(unsigned*)&q2, *(unsigned*)&q3};
        *(uint4*)&Hb[e] = u;
    }
}

// ---------------------------------------------------------------------------
// Kernel 1: fold W_tok into prototypes, emit bf16 + zero d_out (folded memset).
__global__ __launch_bounds__(256)
void k_protoproj(const float* __restrict__ proto,
                 const float* __restrict__ W,
                 unsigned short* __restrict__ Pb,
                 float* __restrict__ outp) {
    int bid = blockIdx.x;            // 256
    int tid = threadIdx.x;
    *(float4*)&outp[bid * 1024 + tid * 4] = (float4){0.f, 0.f, 0.f, 0.f};
    int h = bid >> 4, mr = bid & 15;
    int m0 = mr * 64;
    __shared__ float pl[64][68];
    __shared__ float Wl[64][68];
    int rr = tid >> 2, cg = (tid & 3) * 16;
    #pragma unroll
    for (int i = 0; i < 4; ++i)
        *(float4*)&pl[rr][cg + i * 4] =
            *(const float4*)&proto[rr * D_ + h * 64 + cg + i * 4];
    #pragma unroll
    for (int i = 0; i < 4; ++i)
        *(float4*)&Wl[rr][cg + i * 4] =
            *(const float4*)&W[(h * 64 + rr) * D_ + m0 + cg + i * 4];
    __syncthreads();
    int s = tid & 63, mg = (tid >> 6) * 16;
    float acc[16] = {};
    for (int k = 0; k < 64; ++k) {
        float pv = pl[s][k];
        #pragma unroll
        for (int i = 0; i < 16; ++i) acc[i] += pv * Wl[k][mg + i];
    }
    unsigned short ob[16];
    #pragma unroll
    for (int i = 0; i < 16; ++i) ob[i] = f2bf(0.125f * acc[i]);
    unsigned short* dst = &Pb[(size_t)(h * 64 + s) * D_ + m0 + mg];
    *(uint4*)dst       = *(uint4*)&ob[0];
    *(uint4*)(dst + 8) = *(uint4*)&ob[8];
}

// ---------------------------------------------------------------------------
// Kernel 2 (v10): bf16 MFMA GEMM, 256x256 tile — m201 8-PHASE port.
// 4 phases/K-tile; each phase: {ds_read subtile || 2 gload_lds issue ->
// raw barrier -> lgkmcnt(0)+sched_barrier -> setprio(1) 16 MFMA setprio(0)
// -> barrier}. B-frags read once in P0 (held in regs). WAITC(0) only at
// tile boundary. Accumulation order unchanged (bit-identical vs R18).
// + fused k_cp epilogue (R16, verified).
#define GFENCE  __builtin_amdgcn_sched_barrier(0)

__global__ __launch_bounds__(512, 2)
void k_gemm(const unsigned short* __restrict__ Ab,   // Hb [M_, D_] bf16
            const unsigned short* __restrict__ Bp,   // Pb [N_, D_] bf16
            _Float16* __restrict__ C,                // scores [M_, N_] f16
            float* __restrict__ cp) {                // [B*NH, NCH, 64]
    extern __shared__ unsigned short lds[];
    unsigned short* AsB[2] = {lds,         lds + 16384};   // 2 x 32 KB
    unsigned short* BsB[2] = {lds + 32768, lds + 49152};   // 2 x 32 KB
    int tid = threadIdx.x;                // 0..511
    int bid = blockIdx.x;                 // 0..255
    int wgid = (bid & 7) * 32 + (bid >> 3);
    int bm = wgid >> 2, bn = wgid & 3;    // 64 m-blocks, 4 n-blocks
    int m0 = bm * 256, n0 = bn * 256;
    int l = tid & 63, wv = tid >> 6;      // 8 waves
    int wr = wv >> 2, wc = wv & 3;        // 2M x 4N
    int lr = l & 15, lk = l >> 4;

    int srow = tid >> 3;
    int skgs = (tid & 7) ^ (srow & 7);    // pre-swizzled global 16B group
    const unsigned short* Ap = Ab + (size_t)(m0 + srow) * D_ + skgs * 8;
    const unsigned short* Bq = Bp + (size_t)(n0 + srow) * D_ + skgs * 8;

    f32x4 acc[8][4];
    #pragma unroll
    for (int i = 0; i < 8; ++i)
        #pragma unroll
        for (int j = 0; j < 4; ++j) acc[i][j] = (f32x4){0.f, 0.f, 0.f, 0.f};

#define AFRAG(BUF, M, KK) \
    (*(const short8v*)&AsB[BUF][(wr * 128 + (M) * 16 + lr) * 64 + (((KK) * 4 + lk) ^ (lr & 7)) * 8])
#define BFRAG(BUF, N, KK) \
    (*(const short8v*)&BsB[BUF][(wc * 64 + (N) * 16 + lr) * 64 + (((KK) * 4 + lk) ^ (lr & 7)) * 8])

#define GSTAGE(BUF, K0)                                                         \
    _Pragma("unroll")                                                           \
    for (int i = 0; i < 4; ++i) {                                               \
        __builtin_amdgcn_global_load_lds(                                       \
            (const __attribute__((address_space(1))) void*)(Ap + (size_t)(i * 64) * D_ + (K0)), \
            (__attribute__((address_space(3))) void*)(&AsB[BUF][tid * 8 + i * 4096]), 16, 0, 0); \
        __builtin_amdgcn_global_load_lds(                                       \
            (const __attribute__((address_space(1))) void*)(Bq + (size_t)(i * 64) * D_ + (K0)), \
            (__attribute__((address_space(3))) void*)(&BsB[BUF][tid * 8 + i * 4096]), 16, 0, 0); \
    }

#define STAGE_I(BUF, K0, I)                                                     \
    __builtin_amdgcn_global_load_lds(                                           \
        (const __attribute__((address_space(1))) void*)(Ap + (size_t)((I) * 64) * D_ + (K0)), \
        (__attribute__((address_space(3))) void*)(&AsB[BUF][tid * 8 + (I) * 4096]), 16, 0, 0); \
    __builtin_amdgcn_global_load_lds(                                           \
        (const __attribute__((address_space(1))) void*)(Bq + (size_t)((I) * 64) * D_ + (K0)), \
        (__attribute__((address_space(3))) void*)(&BsB[BUF][tid * 8 + (I) * 4096]), 16, 0, 0);

#define WAITC(N)  asm volatile("s_waitcnt vmcnt(" #N ")" ::: "memory")
#define LGK0      asm volatile("s_waitcnt lgkmcnt(0)" ::: "memory"); GFENCE
#define BARRIER   GFENCE; __builtin_amdgcn_s_barrier(); GFENCE

#define PH_MFMA2(M, A00, A01, A10, A11)                                         \
    _Pragma("unroll")                                                           \
    for (int n = 0; n < 4; ++n) {                                               \
        acc[M][n] = __builtin_amdgcn_mfma_f32_16x16x32_bf16(A00, bfr[n][0], acc[M][n], 0, 0, 0); \
        acc[M][n] = __builtin_amdgcn_mfma_f32_16x16x32_bf16(A01, bfr[n][1], acc[M][n], 0, 0, 0); \
    }                                                                           \
    _Pragma("unroll")                                                           \
    for (int n = 0; n < 4; ++n) {                                               \
        acc[(M)+1][n] = __builtin_amdgcn_mfma_f32_16x16x32_bf16(A10, bfr[n][0], acc[(M)+1][n], 0, 0, 0); \
        acc[(M)+1][n] = __builtin_amdgcn_mfma_f32_16x16x32_bf16(A11, bfr[n][1], acc[(M)+1][n], 0, 0, 0); \
    }

// one K-tile, 4 phases, staging next tile into SB (STG=1) or not (STG=0)
#define KTILE(BUF, SB, K0, STG)                                                 \
    {                                                                           \
        short8v bfr[4][2];                                                      \
        /* ---- phase 0: B-frags + A m0,m1 ---- */                              \
        _Pragma("unroll")                                                       \
        for (int n = 0; n < 4; ++n) {                                           \
            bfr[n][0] = BFRAG(BUF, n, 0);                                       \
            bfr[n][1] = BFRAG(BUF, n, 1);                                       \
        }                                                                       \
        {                                                                       \
            short8v a00 = AFRAG(BUF, 0, 0), a01 = AFRAG(BUF, 0, 1);             \
            short8v a10 = AFRAG(BUF, 1, 0), a11 = AFRAG(BUF, 1, 1);             \
            if (STG) { STAGE_I(SB, K0, 0) }                                     \
            BARRIER;                                                            \
            LGK0;                                                               \
            __builtin_amdgcn_s_setprio(1);                                      \
            PH_MFMA2(0, a00, a01, a10, a11)                                     \
            __builtin_amdgcn_s_setprio(0);                                      \
            BARRIER;                                                            \
        }                                                                       \
        /* ---- phase 1: A m2,m3 ---- */                                        \
        {                                                                       \
            short8v a00 = AFRAG(BUF, 2, 0), a01 = AFRAG(BUF, 2, 1);             \
            short8v a10 = AFRAG(BUF, 3, 0), a11 = AFRAG(BUF, 3, 1);             \
            if (STG) { STAGE_I(SB, K0, 1) }                                     \
            BARRIER;                                                            \
            LGK0;                                                               \
            __builtin_amdgcn_s_setprio(1);                                      \
            PH_MFMA2(2, a00, a01, a10, a11)                                     \
            __builtin_amdgcn_s_setprio(0);                                      \
            BARRIER;                                                            \
        }                                                                       \
        /* ---- phase 2: A m4,m5 ---- */                                        \
        {                                                                       \
            short8v a00 = AFRAG(BUF, 4, 0), a01 = AFRAG(BUF, 4, 1);             \
            short8v a10 = AFRAG(BUF, 5, 0), a11 = AFRAG(BUF, 5, 1);             \
            if (STG) { STAGE_I(SB, K0, 2) }                                     \
            BARRIER;                                                            \
            LGK0;                                                               \
            __builtin_amdgcn_s_setprio(1);                                      \
            PH_MFMA2(4, a00, a01, a10, a11)                                     \
            __builtin_amdgcn_s_setprio(0);                                      \
            BARRIER;                                                            \
        }                                                                       \
        /* ---- phase 3: A m6,m7 + tile-boundary drain ---- */                  \
        {                                                                       \
            short8v a00 = AFRAG(BUF, 6, 0), a01 = AFRAG(BUF, 6, 1);             \
            short8v a10 = AFRAG(BUF, 7, 0), a11 = AFRAG(BUF, 7, 1);             \
            if (STG) { STAGE_I(SB, K0, 3) }                                     \
            BARRIER;                                                            \
            LGK0;                                                               \
            __builtin_amdgcn_s_setprio(1);                                      \
            PH_MFMA2(6, a00, a01, a10, a11)                                     \
            __builtin_amdgcn_s_setprio(0);                                      \
            if (STG) { WAITC(0); }                                              \
            BARRIER;                                                            \
        }                                                                       \
    }

    GSTAGE(0, 0)                          // prologue: tile 0 (8 loads)
    WAITC(0);
    BARRIER;
    for (int t = 0; t < 14; t += 2) {
        KTILE(0, 1, (t + 1) * 64, 1)      // compute t (buf0), stage t+1
        KTILE(1, 0, (t + 2) * 64, 1)      // compute t+1 (buf1), stage t+2
    }
    KTILE(0, 1, 15 * 64, 1)               // compute 14, stage 15
    KTILE(1, 1, 0, 0)                     // compute 15, no staging
#undef KTILE
#undef PH_MFMA2
#undef GSTAGE
#undef STAGE_I
#undef WAITC
#undef LGK0
#undef BARRIER
#undef AFRAG
#undef BFRAG

    // ---- epilogue: store raw f16 scores + fused per-chunk g-products ----
    // acc[m][n][j]: row = m0 + wr*128 + m*16 + lk*4 + j
    //               col = n0 + wc*64  + n*16 + lr   (wave's 64 cols = 1 head)
    int crow = m0 + wr * 128 + lk * 4;
    int ccol = n0 + wc * 64 + lr;
    float pch[4][4];                      // [chunk c2 = m>>1][n]
    #pragma unroll
    for (int c2 = 0; c2 < 4; ++c2)
        #pragma unroll
        for (int n = 0; n < 4; ++n) pch[c2][n] = 1.f;

    #pragma unroll
    for (int m = 0; m < 8; ++m) {
        #pragma unroll
        for (int j = 0; j < 4; ++j) {
            _Float16 s4[4]; float e[4]; float ps = 0.f;
            #pragma unroll
            for (int n = 0; n < 4; ++n) {
                s4[n] = (_Float16)acc[m][n][j];     // f16 rounding = S numerics
                C[(size_t)(crow + m * 16 + j) * N_ + ccol + n * 16] = s4[n];
                e[n] = __expf((float)s4[n]);
                ps += e[n];
            }
            ps += __shfl_xor(ps, 1); ps += __shfl_xor(ps, 2);
            ps += __shfl_xor(ps, 4); ps += __shfl_xor(ps, 8);
            float inv = 1.f / ps;
            int c2 = m >> 1;
            #pragma unroll
            for (int n = 0; n < 4; ++n)
                pch[c2][n] *= 1.f - ALPHA_ * (e[n] * inv);
        }
    }
    // combine the 4 lk row-groups (rows interleave across lanes 16 apart)
    #pragma unroll
    for (int c2 = 0; c2 < 4; ++c2)
        #pragma unroll
        for (int n = 0; n < 4; ++n) {
            pch[c2][n] *= __shfl_xor(pch[c2][n], 16);
            pch[c2][n] *= __shfl_xor(pch[c2][n], 32);
        }
    if (lk == 0) {
        int b  = bm >> 4;
        int h  = bn * 4 + wc;
        int bh = b * NH_ + h;
        int cb = (bm & 15) * 8 + wr * 4;  // chunk base within batch
        #pragma unroll
        for (int c2 = 0; c2 < 4; ++c2)
            #pragma unroll
            for (int n = 0; n < 4; ++n)
                cp[(size_t)(bh * NCH_ + cb + c2) * 64 + n * 16 + lr] = pch[c2][n];
    }
}

// ---------------------------------------------------------------------------
// Kernel 3b: PARALLEL cross-chunk exclusive suffix scan (unchanged).
__global__ __launch_bounds__(256)
void k_scan(const float* __restrict__ cp, float* __restrict__ csuf) {
    int bh = blockIdx.x;                  // 64
    __shared__ float buf[128][64];        // 32 KB
    __shared__ float segp[4][64];
    int tid = threadIdx.x;
    #pragma unroll
    for (int i = 0; i < 8; ++i) {
        int e = tid * 4 + i * 1024;
        int c = e >> 6, sc = e & 63;
        *(float4*)&buf[c][sc] = *(const float4*)&cp[(bh * NCH_ + c) * 64 + sc];
    }
    __syncthreads();
    int s = tid & 63, seg = tid >> 6;
    float pp = 1.f;
    #pragma unroll
    for (int r = 0; r < 32; ++r) pp *= buf[seg * 32 + r][s];
    segp[seg][s] = pp;
    __syncthreads();
    float suf = 1.f;
    if (seg <= 2) suf *= segp[3][s];
    if (seg <= 1) suf *= segp[2][s];
    if (seg == 0) suf *= segp[1][s];
    #pragma unroll
    for (int r = 31; r >= 0; --r) {
        int c = seg * 32 + r;
        csuf[(bh * NCH_ + c) * 64 + s] = suf;   // EXCLUSIVE suffix
        suf *= buf[c][s];
    }
}

// ---------------------------------------------------------------------------
// Kernel 4 (unchanged R16/R18): softmax + weff walk + MFMA output accumulation.
__global__ __launch_bounds__(256)
void k_out_mfma(const _Float16* __restrict__ S,       // raw scores
                const unsigned short* __restrict__ Hb,// bf16 H
                const float* __restrict__ csuf,
                float* __restrict__ out) {
    int bx = blockIdx.x;                  // 1024
    int cf = bx & 15, h = (bx >> 4) & 15, b = bx >> 8;
    __shared__ _Float16 ws16[64][72];           // softmaxed w
    __shared__ unsigned short tmp[64][72];      // staged Hb rows
    __shared__ float ppl[4][64];                // per-16-row g partial products
    __shared__ _Float16 wt[8 * 64 * 8];         // w_eff^T subtiled [tg][s][8]
    __shared__ _Float16 hd[8 * 64 * 8];         // H^T    subtiled [tg][d][8]
    int tid = threadIdx.x;
    int lr0 = tid >> 3, lc = (tid & 7) * 8;     // load role: rows lr0, lr0+32
    int s = tid & 63, q = tid >> 6;             // walk/transpose role
    int fr = s & 15, fk = s >> 4, wv = q;       // mfma role

    // T14: issue it=0 loads first so they overlap the csuf loads
    size_t rr0 = (size_t)(b * T_ + cf * 256 + lr0) * N_ + h * 64 + lc;
    f16x8  sv0 = *(const f16x8*)(S + rr0);
    f16x8  sv1 = *(const f16x8*)(S + rr0 + (size_t)32 * N_);
    short8v hv0 = *(const short8v*)(Hb + rr0);
    short8v hv1 = *(const short8v*)(Hb + rr0 + (size_t)32 * N_);

    // prologue: su[k] = exclusive suffix of chunk (cf*8 + k)
    int cbase = (b * NH_ + h) * NCH_ + cf * 8;
    float su[8];
    #pragma unroll
    for (int k = 0; k < 8; ++k)
        su[k] = csuf[(cbase + k) * 64 + s];

    f32x4 acc[4];
    #pragma unroll
    for (int n = 0; n < 4; ++n) acc[n] = (f32x4){0.f, 0.f, 0.f, 0.f};

    for (int it = 0; it < 4; ++it) {
        // softmax per row (8-lane group, no max-sub; |score| small)
        _Float16 w0[8], w1[8];
        {
            float e[8]; float ps = 0.f;
            #pragma unroll
            for (int j = 0; j < 8; ++j) { e[j] = __expf((float)sv0[j]); ps += e[j]; }
            ps += __shfl_xor(ps, 1); ps += __shfl_xor(ps, 2); ps += __shfl_xor(ps, 4);
            float inv = 1.f / ps;
            #pragma unroll
            for (int j = 0; j < 8; ++j) w0[j] = (_Float16)(e[j] * inv);
        }
        {
            float e[8]; float ps = 0.f;
            #pragma unroll
            for (int j = 0; j < 8; ++j) { e[j] = __expf((float)sv1[j]); ps += e[j]; }
            ps += __shfl_xor(ps, 1); ps += __shfl_xor(ps, 2); ps += __shfl_xor(ps, 4);
            float inv = 1.f / ps;
            #pragma unroll
            for (int j = 0; j < 8; ++j) w1[j] = (_Float16)(e[j] * inv);
        }
        // (barrier A removed: prior iter's barrier D already ordered all
        //  ws16/tmp readers; MFMA between D and here reads only wt/hd)
        *(f16x8*)&ws16[lr0][lc]      = *(f16x8*)w0;
        *(f16x8*)&ws16[lr0 + 32][lc] = *(f16x8*)w1;
        *(short8v*)&tmp[lr0][lc]      = hv0;
        *(short8v*)&tmp[lr0 + 32][lc] = hv1;
        __syncthreads();                  // B: ws16 + tmp visible
        // T14: issue next iteration's loads now (regs free, latency hidden)
        if (it < 3) {
            size_t rn = rr0 + (size_t)((it + 1) * 64) * N_;
            sv0 = *(const f16x8*)(S + rn);
            sv1 = *(const f16x8*)(S + rn + (size_t)32 * N_);
            hv0 = *(const short8v*)(Hb + rn);
            hv1 = *(const short8v*)(Hb + rn + (size_t)32 * N_);
        }
        // ppl: partial product of g over this thread's 16 rows
        {
            float pp = 1.f;
            #pragma unroll
            for (int r = 0; r < 16; ++r)
                pp *= 1.f - ALPHA_ * (float)ws16[q * 16 + r][s];
            ppl[q][s] = pp;
        }
        // transpose Hb: thread (q,s): tg = q and q+4, cvt bf16 -> f16
        #pragma unroll
        for (int x = 0; x < 2; ++x) {
            int tg = q + x * 4;
            _Float16 hreg[8];
            #pragma unroll
            for (int r = 0; r < 8; ++r) {
                unsigned short ub = tmp[tg * 8 + r][s];
                hreg[r] = (_Float16)__uint_as_float((unsigned)ub << 16);
            }
            *(f16x8*)&hd[(tg * 64 + s) * 8] = *(f16x8*)hreg;
        }
        __syncthreads();                  // C: ppl + hd visible
        // walk: rows q*16..q*16+15 backward; chunk split at q<2 | q>=2
        {
            float suf = (q >= 2) ? su[it * 2 + 1] : su[it * 2];
            if (q == 2) suf *= ppl[3][s];
            if (q == 0) suf *= ppl[1][s];
            _Float16 wr16[16];
            #pragma unroll
            for (int r = 15; r >= 0; --r) {
                float wv_ = (float)ws16[q * 16 + r][s];
                wr16[r] = (_Float16)(ALPHA_ * wv_ * suf);
                suf *= 1.f - ALPHA_ * wv_;
            }
            *(f16x8*)&wt[((2 * q)     * 64 + s) * 8] = *(f16x8*)&wr16[0];
            *(f16x8*)&wt[((2 * q + 1) * 64 + s) * 8] = *(f16x8*)&wr16[8];
        }
        __syncthreads();                  // D: wt visible
        // MFMA: wave wv -> s-block wv*16, all 64 d; K=64 = 2 k-steps
        #pragma unroll
        for (int kk = 0; kk < 2; ++kk) {
            int tg = kk * 4 + fk;
            f16x8 af = *(const f16x8*)&wt[(tg * 64 + wv * 16 + fr) * 8];
            #pragma unroll
            for (int n = 0; n < 4; ++n) {
                f16x8 bf = *(const f16x8*)&hd[(tg * 64 + n * 16 + fr) * 8];
                acc[n] = __builtin_amdgcn_mfma_f32_16x16x32_f16(
                    af, bf, acc[n], 0, 0, 0);
            }
        }
    }
    // D layout: row (s-dim) = fk*4 + j, col (d-dim) = fr
    #pragma unroll
    for (int n = 0; n < 4; ++n)
        #pragma unroll
        for (int j = 0; j < 4; ++j)
            atomicAdd(&out[((b * NS_ + wv * 16 + fk * 4 + j) * NH_ + h) * HD_
                           + n * 16 + fr],
                      acc[n][j]);
}

// ---------------------------------------------------------------------------
extern "C" void kernel_launch(void* const* d_in, const int* in_sizes, int n_in,
                              void* d_out, int out_size, void* d_ws, size_t ws_size,
                              hipStream_t stream) {
    const float* H     = (const float*)d_in[0];
    const float* proto = (const float*)d_in[1];
    const float* W     = (const float*)d_in[2];
    float* out = (float*)d_out;
    char*  ws  = (char*)d_ws;

    _Float16*       S  = (_Float16*)ws;                                  // 32 MB
    unsigned short* Hb = (unsigned short*)(ws + (size_t)M_ * N_ * 2);    // 32 MB
    unsigned short* Pb = (unsigned short*)(ws + (size_t)M_ * N_ * 2
                                              + (size_t)M_ * D_ * 2);    // 2 MB
    float* cp   = (float*)((char*)Pb + (size_t)N_ * D_ * 2);             // 2 MB
    float* csuf = cp + (size_t)B_ * NH_ * NCH_ * 64;                     // 2 MB

    // allow 128 KB dynamic LDS for the 256^2 GEMM (host-side, capture-safe)
    hipFuncSetAttribute((const void*)k_gemm,
                        hipFuncAttributeMaxDynamicSharedMemorySize, 131072);

    k_h2bf      <<<2048,      256, 0,      stream>>>(H, Hb);
    k_protoproj <<<256,       256, 0,      stream>>>(proto, W, Pb, out);
    k_gemm      <<<256,       512, 131072, stream>>>(Hb, Pb, S, cp);
    k_scan      <<<B_*NH_,    256, 0,      stream>>>(cp, csuf);
    k_out_mfma  <<<B_*NH_*16, 256, 0,      stream>>>(S, Hb, csuf, out);
}